// Round 10
// baseline (296.459 us; speedup 1.0000x reference)
//
#include <hip/hip_runtime.h>
#include <hip/hip_bf16.h>

typedef unsigned int uint;
typedef unsigned short ushort;
typedef __attribute__((ext_vector_type(8))) short short8;
typedef __attribute__((ext_vector_type(4))) short short4v;
typedef __attribute__((ext_vector_type(4))) float f32x4;

#define LEAKY 0.2f

__device__ __forceinline__ ushort f2bf(float f) {
  __hip_bfloat16 h = __float2bfloat16(f);
  return __builtin_bit_cast(ushort, h);
}
__device__ __forceinline__ float bf2f(ushort u) {
  uint v = ((uint)u) << 16;
  return __builtin_bit_cast(float, v);
}
__device__ __forceinline__ void gload_lds16(const void* g, void* l) {
  __builtin_amdgcn_global_load_lds(
      (const __attribute__((address_space(1))) void*)g,
      (__attribute__((address_space(3))) void*)l, 16, 0, 0);
}

// ---- both W transposes + bf16 convert in one launch -----------------------
__global__ void convw_all(const float* __restrict__ W1, ushort* __restrict__ W1t,
                          const float* __restrict__ W2, ushort* __restrict__ W2t) {
  int idx = blockIdx.x * 256 + threadIdx.x;
  const int n1 = 512 * 1024;
  if (idx < n1) {
    int nrow = idx >> 10, k = idx & 1023;
    W1t[idx] = f2bf(W1[(size_t)k * 512 + nrow]);
  } else {
    idx -= n1;
    if (idx < 256 * 512) {
      int nrow = idx >> 9, k = idx & 511;
      W2t[idx] = f2bf(W2[(size_t)k * 256 + nrow]);
    }
  }
}

// ---------------- CSR build ------------------------------------------------
__global__ void zero2(int* a, int* b, int n) {
  int i = blockIdx.x * 256 + threadIdx.x;
  if (i < n) { a[i] = 0; b[i] = 0; }
}

__global__ void hist(const int* __restrict__ dst, int E, int n, int* cnt) {
  int e = blockIdx.x * 256 + threadIdx.x;
  if (e >= E + n) return;
  int d = (e < E) ? dst[e] : (e - E);
  atomicAdd(&cnt[d], 1);
}

// single-block scan, shfl-based (few barriers). n <= 32768.
__global__ __launch_bounds__(1024) void scan_fast(const int* __restrict__ cnt,
                                                  int* __restrict__ rp, int n) {
  __shared__ int wsum[16];
  __shared__ int woff[16];
  const int t = threadIdx.x;
  const int per = (n + 1023) / 1024;
  const int base = t * per;
  int local[32];
  int s = 0;
#pragma unroll
  for (int i = 0; i < 32; i++) {
    if (i >= per) break;
    int idx = base + i;
    int v = (idx < n) ? cnt[idx] : 0;
    local[i] = s;
    s += v;
  }
  const int lane = t & 63, wave = t >> 6;
  int incl = s;
#pragma unroll
  for (int off = 1; off < 64; off <<= 1) {
    int v = __shfl_up(incl, off);
    if (lane >= off) incl += v;
  }
  if (lane == 63) wsum[wave] = incl;
  __syncthreads();
  if (wave == 0 && lane < 16) {
    int v = wsum[lane];
    int wi = v;
#pragma unroll
    for (int off = 1; off < 16; off <<= 1) {
      int u = __shfl_up(wi, off);
      if (lane >= off) wi += u;
    }
    woff[lane] = wi - v;  // exclusive
  }
  __syncthreads();
  const int gexcl = woff[wave] + (incl - s);
#pragma unroll
  for (int i = 0; i < 32; i++) {
    if (i >= per) break;
    int idx = base + i;
    if (idx < n) rp[idx] = gexcl + local[i];
  }
  if (t == 1023) rp[n] = woff[15] + incl;
}

__global__ void scatter(const int* __restrict__ src, const int* __restrict__ dst,
                        int E, int n, const int* __restrict__ rp,
                        int* fill, int* __restrict__ csr) {
  int e = blockIdx.x * 256 + threadIdx.x;
  if (e >= E + n) return;
  int s, d;
  if (e < E) { s = src[e]; d = dst[e]; } else { s = d = e - E; }
  int pos = rp[d] + atomicAdd(&fill[d], 1);
  csr[pos] = s;
}

// ------- BM=256 wide GEMM (min staged bytes) + fused logit epilogue --------
// C[M,N]=A[M,K]*Bt[N,K]^T. 1024 thr, 16 waves (4Mx4N, wave tile 64x64),
// BM=256 BN=256 BK=32. Staged bytes = M*N*K*(4/BN+2/BM) = 369MB (GEMM1),
// 25% less than the 128x256 config; time tracks staged bytes / ~6 TB/s.
// Same proven loop: stage(glds16, XOR-swz src) -> vmcnt(0) -> barrier.
// Epilogue: HEADS=8 -> per-wave head logits via r16-shfl (one head/wave);
//           HEADS=1 -> LDS cross-wave reduce (reuses As scratch).
template <int ABYTES, int HEADS>
__global__ __launch_bounds__(1024) void gemm_fl(
    const void* __restrict__ Av, const ushort* __restrict__ Bt,
    ushort* __restrict__ C, float* __restrict__ al_s, float* __restrict__ al_d,
    const float* __restrict__ as_vec, const float* __restrict__ ad_vec,
    int M, int K, int N) {
  constexpr int BM = 256, BN = 256, BK = 32;
  constexpr int SPRA = (BK * ABYTES) / 16;    // 8 (fp32) or 4 (bf16)
  constexpr int A_ITER = (BM * SPRA) / 1024;  // 2 or 1
  __shared__ __align__(16) char As[BM * BK * ABYTES];  // 32KB / 16KB
  __shared__ __align__(16) char Bs[BN * BK * 2];       // 16KB
  const int tid = threadIdx.x;
  const int wave = tid >> 6, lane = tid & 63;
  const int g = lane >> 4, r16 = lane & 15;
  const int nby = N / BN;
  const int bx = (int)blockIdx.x / nby;
  const int by = (int)blockIdx.x - bx * nby;
  const int bm = bx * BM, bn = by * BN;
  const int wm = (wave >> 2) * 64, wn = (wave & 3) * 64;

  f32x4 acc[4][4] = {};
  const char* A = (const char*)Av;

  for (int k0 = 0; k0 < K; k0 += BK) {
#pragma unroll
    for (int i = 0; i < A_ITER; i++) {
      int slot = i * 1024 + tid;
      int row = slot / SPRA;
      int cp = slot - row * SPRA;
      int key = (ABYTES == 4) ? (row & 7) : ((row >> 1) & 3);
      int cl = cp ^ key;
      int arow = bm + row;
      arow = arow < M ? arow : M - 1;  // clamp pad rows (stores guarded)
      const char* gp = A + ((size_t)arow * K + k0) * ABYTES + cl * 16;
      char* lp = As + (i * 1024 + wave * 64) * 16;
      gload_lds16(gp, lp);
    }
    {  // B: BN*4 = 1024 slots, one iter
      int slot = tid;
      int row = slot >> 2;
      int cp = slot & 3;
      int cl = cp ^ ((row >> 1) & 3);
      const char* gp = (const char*)(Bt + (size_t)(bn + row) * K + k0 + cl * 8);
      char* lp = Bs + (size_t)(wave * 64) * 16;
      gload_lds16(gp, lp);
    }
    asm volatile("s_waitcnt vmcnt(0)" ::: "memory");
    __syncthreads();

    short8 af[4], bfr[4];
#pragma unroll
    for (int mi = 0; mi < 4; mi++) {
      int row = wm + mi * 16 + r16;
      if constexpr (ABYTES == 4) {
        int key = row & 7;
        f32x4 lo = *(const f32x4*)(As + (row * 8 + ((2 * g) ^ key)) * 16);
        f32x4 hi = *(const f32x4*)(As + (row * 8 + ((2 * g + 1) ^ key)) * 16);
        short8 s;
#pragma unroll
        for (int qq = 0; qq < 4; qq++) {
          s[qq] = (short)f2bf(lo[qq]);
          s[qq + 4] = (short)f2bf(hi[qq]);
        }
        af[mi] = s;
      } else {
        int key = (row >> 1) & 3;
        af[mi] = *(const short8*)(As + (row * 4 + (g ^ key)) * 16);
      }
    }
#pragma unroll
    for (int ni = 0; ni < 4; ni++) {
      int row = wn + ni * 16 + r16;
      int key = (row >> 1) & 3;
      bfr[ni] = *(const short8*)(Bs + (row * 4 + (g ^ key)) * 16);
    }
#pragma unroll
    for (int mi = 0; mi < 4; mi++)
#pragma unroll
      for (int ni = 0; ni < 4; ni++)
        acc[mi][ni] = __builtin_amdgcn_mfma_f32_16x16x32_bf16(
            af[mi], bfr[ni], acc[mi][ni], 0, 0, 0);
    __syncthreads();
  }

  // C store (bf16)
#pragma unroll
  for (int mi = 0; mi < 4; mi++) {
#pragma unroll
    for (int j = 0; j < 4; j++) {
      int row = bm + wm + mi * 16 + g * 4 + j;
      if (row < M) {
#pragma unroll
        for (int ni = 0; ni < 4; ni++) {
          int col = bn + wn + ni * 16 + r16;
          C[(size_t)row * N + col] = f2bf(acc[mi][ni][j]);
        }
      }
    }
  }

  // ---- fused logits epilogue ----
  if constexpr (HEADS == 8) {
    const int head = (bn + wn) >> 6;  // one head per wave (C=64)
    float asr[4], adr[4];
#pragma unroll
    for (int ni = 0; ni < 4; ni++) {
      asr[ni] = as_vec[head * 64 + ni * 16 + r16];
      adr[ni] = ad_vec[head * 64 + ni * 16 + r16];
    }
#pragma unroll
    for (int mi = 0; mi < 4; mi++) {
#pragma unroll
      for (int j = 0; j < 4; j++) {
        float ps = 0.f, pd = 0.f;
#pragma unroll
        for (int ni = 0; ni < 4; ni++) {
          ps += acc[mi][ni][j] * asr[ni];
          pd += acc[mi][ni][j] * adr[ni];
        }
#pragma unroll
        for (int off = 1; off < 16; off <<= 1) {
          ps += __shfl_xor(ps, off);
          pd += __shfl_xor(pd, off);
        }
        if (r16 == 0) {
          int row = bm + wm + mi * 16 + g * 4 + j;
          if (row < M) {
            al_s[row * 8 + head] = ps;
            al_d[row * 8 + head] = pd;
          }
        }
      }
    }
  } else {
    // HEADS==1, C=256: 16-wave cross reduce via LDS (reuse As: 8KB)
    float* sred = (float*)As;           // [16][64]
    float* dred = sred + 16 * 64;       // [16][64]
    float asr[4], adr[4];
#pragma unroll
    for (int ni = 0; ni < 4; ni++) {
      asr[ni] = as_vec[wn + ni * 16 + r16];
      adr[ni] = ad_vec[wn + ni * 16 + r16];
    }
    __syncthreads();
#pragma unroll
    for (int mi = 0; mi < 4; mi++) {
#pragma unroll
      for (int j = 0; j < 4; j++) {
        float ps = 0.f, pd = 0.f;
#pragma unroll
        for (int ni = 0; ni < 4; ni++) {
          ps += acc[mi][ni][j] * asr[ni];
          pd += acc[mi][ni][j] * adr[ni];
        }
#pragma unroll
        for (int off = 1; off < 16; off <<= 1) {
          ps += __shfl_xor(ps, off);
          pd += __shfl_xor(pd, off);
        }
        if (r16 == 0) {
          int rloc = mi * 16 + g * 4 + j;  // 0..63 within wave
          sred[wave * 64 + rloc] = ps;
          dred[wave * 64 + rloc] = pd;
        }
      }
    }
    __syncthreads();
    if (tid < 256) {
      int wg = tid >> 6;     // which wm group (4 waves share it)
      int rl = tid & 63;
      int w0 = wg * 4;
      float s = sred[(w0 + 0) * 64 + rl] + sred[(w0 + 1) * 64 + rl] +
                sred[(w0 + 2) * 64 + rl] + sred[(w0 + 3) * 64 + rl];
      float d = dred[(w0 + 0) * 64 + rl] + dred[(w0 + 1) * 64 + rl] +
                dred[(w0 + 2) * 64 + rl] + dred[(w0 + 3) * 64 + rl];
      int row = bm + tid;
      if (row < M) {
        al_s[row] = s;
        al_d[row] = d;
      }
    }
  }
}

// ---------------- segment softmax + aggregation (single pass, no max) ------
__global__ void agg1(const int* __restrict__ rp, const int* __restrict__ csr,
                     const ushort* __restrict__ h1, const float* __restrict__ al_s,
                     const float* __restrict__ al_d, const float* __restrict__ b1,
                     ushort* __restrict__ h2in, int n) {
  int node = blockIdx.x * 4 + (threadIdx.x >> 6);
  if (node >= n) return;
  int lane = threadIdx.x & 63;
  int head = lane >> 3, c0 = lane * 8;
  float ad = al_d[node * 8 + head];
  int beg = rp[node], end = rp[node + 1];
  float sum = 0.f;
  float acc[8] = {};
  int j = beg;
  for (; j + 8 <= end; j += 8) {
    int sx[8];
    float e[8];
    short8 v[8];
#pragma unroll
    for (int u = 0; u < 8; u++) sx[u] = csr[j + u];
#pragma unroll
    for (int u = 0; u < 8; u++) e[u] = al_s[sx[u] * 8 + head] + ad;
#pragma unroll
    for (int u = 0; u < 8; u++) v[u] = *(const short8*)&h1[(size_t)sx[u] * 512 + c0];
#pragma unroll
    for (int u = 0; u < 8; u++) {
      float eu = e[u];
      eu = eu > 0.f ? eu : LEAKY * eu;
      float p = __expf(eu);
      sum += p;
#pragma unroll
      for (int qq = 0; qq < 8; qq++) acc[qq] += p * bf2f((ushort)v[u][qq]);
    }
  }
  for (; j < end; j++) {
    int s = csr[j];
    float e = al_s[s * 8 + head] + ad;
    e = e > 0.f ? e : LEAKY * e;
    float p = __expf(e);
    sum += p;
    short8 hv = *(const short8*)&h1[(size_t)s * 512 + c0];
#pragma unroll
    for (int qq = 0; qq < 8; qq++) acc[qq] += p * bf2f((ushort)hv[qq]);
  }
  float inv = 1.0f / sum;
  short8 o;
#pragma unroll
  for (int qq = 0; qq < 8; qq++) {
    float rr = acc[qq] * inv + b1[c0 + qq];
    rr = rr > 0.f ? rr : (__expf(rr) - 1.0f);  // ELU alpha=1
    o[qq] = (short)f2bf(rr);
  }
  *(short8*)&h2in[(size_t)node * 512 + c0] = o;
}

__global__ void agg2(const int* __restrict__ rp, const int* __restrict__ csr,
                     const ushort* __restrict__ h2, const float* __restrict__ al_s,
                     const float* __restrict__ al_d, const float* __restrict__ b2,
                     float* __restrict__ out, int n) {
  int node = blockIdx.x * 4 + (threadIdx.x >> 6);
  if (node >= n) return;
  int lane = threadIdx.x & 63;
  int c0 = lane * 4;
  float ad = al_d[node];
  int beg = rp[node], end = rp[node + 1];
  float sum = 0.f;
  float a0 = 0.f, a1 = 0.f, a2 = 0.f, a3 = 0.f;
  int j = beg;
  for (; j + 8 <= end; j += 8) {
    int sx[8];
    float e[8];
    short4v v[8];
#pragma unroll
    for (int u = 0; u < 8; u++) sx[u] = csr[j + u];
#pragma unroll
    for (int u = 0; u < 8; u++) e[u] = al_s[sx[u]] + ad;
#pragma unroll
    for (int u = 0; u < 8; u++) v[u] = *(const short4v*)&h2[(size_t)sx[u] * 256 + c0];
#pragma unroll
    for (int u = 0; u < 8; u++) {
      float eu = e[u];
      eu = eu > 0.f ? eu : LEAKY * eu;
      float p = __expf(eu);
      sum += p;
      a0 += p * bf2f((ushort)v[u][0]);
      a1 += p * bf2f((ushort)v[u][1]);
      a2 += p * bf2f((ushort)v[u][2]);
      a3 += p * bf2f((ushort)v[u][3]);
    }
  }
  for (; j < end; j++) {
    int s = csr[j];
    float e = al_s[s] + ad;
    e = e > 0.f ? e : LEAKY * e;
    float p = __expf(e);
    sum += p;
    short4v hv = *(const short4v*)&h2[(size_t)s * 256 + c0];
    a0 += p * bf2f((ushort)hv[0]);
    a1 += p * bf2f((ushort)hv[1]);
    a2 += p * bf2f((ushort)hv[2]);
    a3 += p * bf2f((ushort)hv[3]);
  }
  float inv = 1.0f / sum;
  f32x4 o;
  o[0] = a0 * inv + b2[c0 + 0];
  o[1] = a1 * inv + b2[c0 + 1];
  o[2] = a2 * inv + b2[c0 + 2];
  o[3] = a3 * inv + b2[c0 + 3];
  *(f32x4*)&out[(size_t)node * 256 + c0] = o;
}

// ---------------------------------------------------------------------------
extern "C" void kernel_launch(void* const* d_in, const int* in_sizes, int n_in,
                              void* d_out, int out_size, void* d_ws, size_t ws_size,
                              hipStream_t stream) {
  const float* x = (const float*)d_in[0];
  const int* ei = (const int*)d_in[1];
  const float* W1 = (const float*)d_in[2];
  const float* a1s = (const float*)d_in[3];
  const float* a1d = (const float*)d_in[4];
  const float* b1 = (const float*)d_in[5];
  const float* W2 = (const float*)d_in[6];
  const float* a2s = (const float*)d_in[7];
  const float* a2d = (const float*)d_in[8];
  const float* b2 = (const float*)d_in[9];
  float* out = (float*)d_out;

  const int n = in_sizes[0] / 1024;  // 30000
  const int E = in_sizes[1] / 2;     // 480000
  const int K1 = 1024, C1 = 512, C2 = 256;

  char* ws = (char*)d_ws;
  ushort* h1 = (ushort*)(ws + 0);            // [n,512] bf16
  ushort* h2in = (ushort*)(ws + 31000000);   // [n,512] bf16 (elu out)
  ushort* h2 = (ushort*)(ws + 62000000);     // [n,256] bf16
  float* al_s = (float*)(ws + 78000000);     // [n,8]
  float* al_d = (float*)(ws + 79000000);     // [n,8]
  float* al2s = (float*)(ws + 80000000);     // [n]
  float* al2d = (float*)(ws + 80200000);     // [n]
  ushort* W1t = (ushort*)(ws + 80400000);    // [512,1024] bf16
  ushort* W2t = (ushort*)(ws + 81600000);    // [256,512] bf16
  int* cnt = (int*)(ws + 82000000);          // [n]
  int* rp = (int*)(ws + 82200000);           // [n+1]
  int* fill = (int*)(ws + 82400000);         // [n]
  int* csr = (int*)(ws + 82600000);          // [E+n]

  const int* esrc = ei;
  const int* edst = ei + E;
  const int ET = E + n;

  convw_all<<<(C1 * K1 + C2 * C1 + 255) / 256, 256, 0, stream>>>(W1, W1t, W2, W2t);
  zero2<<<(n + 255) / 256, 256, 0, stream>>>(cnt, fill, n);
  hist<<<(ET + 255) / 256, 256, 0, stream>>>(edst, E, n, cnt);
  scan_fast<<<1, 1024, 0, stream>>>(cnt, rp, n);
  scatter<<<(ET + 255) / 256, 256, 0, stream>>>(esrc, edst, E, n, rp, fill, csr);

  const int gx1 = ((n + 255) / 256) * (C1 / 256);
  gemm_fl<4, 8><<<gx1, 1024, 0, stream>>>(x, W1t, h1, al_s, al_d, a1s, a1d, n, K1, C1);
  agg1<<<(n + 3) / 4, 256, 0, stream>>>(rp, csr, h1, al_s, al_d, b1, h2in, n);

  const int gx2 = ((n + 255) / 256) * (C2 / 256);
  gemm_fl<2, 1><<<gx2, 1024, 0, stream>>>(h2in, W2t, h2, al2s, al2d, a2s, a2d, n, C1, C2);
  agg2<<<(n + 3) / 4, 256, 0, stream>>>(rp, csr, h2, al2s, al2d, b2, out, n);
}

// Round 11
// 270.996 us; speedup vs baseline: 1.0940x; 1.0940x over previous
//
#include <hip/hip_runtime.h>
#include <hip/hip_bf16.h>

typedef unsigned int uint;
typedef unsigned short ushort;
typedef __attribute__((ext_vector_type(8))) short short8;
typedef __attribute__((ext_vector_type(4))) short short4v;
typedef __attribute__((ext_vector_type(4))) float f32x4;

#define LEAKY 0.2f

__device__ __forceinline__ ushort f2bf(float f) {
  __hip_bfloat16 h = __float2bfloat16(f);
  return __builtin_bit_cast(ushort, h);
}
__device__ __forceinline__ float bf2f(ushort u) {
  uint v = ((uint)u) << 16;
  return __builtin_bit_cast(float, v);
}
__device__ __forceinline__ void gload_lds16(const void* g, void* l) {
  __builtin_amdgcn_global_load_lds(
      (const __attribute__((address_space(1))) void*)g,
      (__attribute__((address_space(3))) void*)l, 16, 0, 0);
}

// ---- both W transposes + bf16 convert + cnt/fill zeroing, one launch ------
__global__ void convw_all(const float* __restrict__ W1, ushort* __restrict__ W1t,
                          const float* __restrict__ W2, ushort* __restrict__ W2t,
                          int* __restrict__ cnt, int* __restrict__ fill, int n) {
  int idx = blockIdx.x * 256 + threadIdx.x;
  if (idx < n) { cnt[idx] = 0; fill[idx] = 0; }
  const int n1 = 512 * 1024;
  if (idx < n1) {
    int nrow = idx >> 10, k = idx & 1023;
    W1t[idx] = f2bf(W1[(size_t)k * 512 + nrow]);
  } else {
    idx -= n1;
    if (idx < 256 * 512) {
      int nrow = idx >> 9, k = idx & 511;
      W2t[idx] = f2bf(W2[(size_t)k * 256 + nrow]);
    }
  }
}

// ---------------- CSR build ------------------------------------------------
__global__ void hist(const int* __restrict__ dst, int E, int n, int* cnt) {
  int e = blockIdx.x * 256 + threadIdx.x;
  if (e >= E + n) return;
  int d = (e < E) ? dst[e] : (e - E);
  atomicAdd(&cnt[d], 1);
}

// single-block scan, shfl-based (few barriers). n <= 32768.
__global__ __launch_bounds__(1024) void scan_fast(const int* __restrict__ cnt,
                                                  int* __restrict__ rp, int n) {
  __shared__ int wsum[16];
  __shared__ int woff[16];
  const int t = threadIdx.x;
  const int per = (n + 1023) / 1024;
  const int base = t * per;
  int local[32];
  int s = 0;
#pragma unroll
  for (int i = 0; i < 32; i++) {
    if (i >= per) break;
    int idx = base + i;
    int v = (idx < n) ? cnt[idx] : 0;
    local[i] = s;
    s += v;
  }
  const int lane = t & 63, wave = t >> 6;
  int incl = s;
#pragma unroll
  for (int off = 1; off < 64; off <<= 1) {
    int v = __shfl_up(incl, off);
    if (lane >= off) incl += v;
  }
  if (lane == 63) wsum[wave] = incl;
  __syncthreads();
  if (wave == 0 && lane < 16) {
    int v = wsum[lane];
    int wi = v;
#pragma unroll
    for (int off = 1; off < 16; off <<= 1) {
      int u = __shfl_up(wi, off);
      if (lane >= off) wi += u;
    }
    woff[lane] = wi - v;  // exclusive
  }
  __syncthreads();
  const int gexcl = woff[wave] + (incl - s);
#pragma unroll
  for (int i = 0; i < 32; i++) {
    if (i >= per) break;
    int idx = base + i;
    if (idx < n) rp[idx] = gexcl + local[i];
  }
  if (t == 1023) rp[n] = woff[15] + incl;
}

__global__ void scatter(const int* __restrict__ src, const int* __restrict__ dst,
                        int E, int n, const int* __restrict__ rp,
                        int* fill, int* __restrict__ csr) {
  int e = blockIdx.x * 256 + threadIdx.x;
  if (e >= E + n) return;
  int s, d;
  if (e < E) { s = src[e]; d = dst[e]; } else { s = d = e - E; }
  int pos = rp[d] + atomicAdd(&fill[d], 1);
  csr[pos] = s;
}

// ------- R3-proven wide GEMM + fused attention-logit epilogue --------------
// C[M,N]=A[M,K]*Bt[N,K]^T, h stored bf16. 512 thr, 8 waves (2Mx4N),
// BM=128 BN=256 BK=32, single-buffer LDS, stage->vmcnt(0)->barrier loop
// (measured best config: R3 83us / R9-fused 92us GEMM1; five structural
// alternatives — dbuf, BK=64, B-direct, narrow blocks, BM=256 — all slower).
template <int ABYTES, int HEADS>
__global__ __launch_bounds__(512) void gemm_fl(
    const void* __restrict__ Av, const ushort* __restrict__ Bt,
    ushort* __restrict__ C, float* __restrict__ al_s, float* __restrict__ al_d,
    const float* __restrict__ as_vec, const float* __restrict__ ad_vec,
    int M, int K, int N) {
  constexpr int BM = 128, BN = 256, BK = 32;
  constexpr int SPRA = (BK * ABYTES) / 16;
  constexpr int A_ITER = (BM * SPRA) / 512;
  __shared__ __align__(16) char As[BM * BK * ABYTES];  // 16KB / 8KB
  __shared__ __align__(16) char Bs[BN * BK * 2];       // 16KB
  const int tid = threadIdx.x;
  const int wave = tid >> 6, lane = tid & 63;
  const int g = lane >> 4, r16 = lane & 15;
  const int nby = N / BN;
  const int bx = (int)blockIdx.x / nby;
  const int by = (int)blockIdx.x - bx * nby;
  const int bm = bx * BM, bn = by * BN;
  const int wm = (wave >> 2) * 64, wn = (wave & 3) * 64;

  f32x4 acc[4][4] = {};
  const char* A = (const char*)Av;

  for (int k0 = 0; k0 < K; k0 += BK) {
#pragma unroll
    for (int i = 0; i < A_ITER; i++) {
      int slot = i * 512 + tid;
      int row = slot / SPRA;
      int cp = slot - row * SPRA;
      int key = (ABYTES == 4) ? (row & 7) : ((row >> 1) & 3);
      int cl = cp ^ key;
      int arow = bm + row;
      arow = arow < M ? arow : M - 1;
      const char* gp = A + ((size_t)arow * K + k0) * ABYTES + cl * 16;
      char* lp = As + (i * 512 + wave * 64) * 16;
      gload_lds16(gp, lp);
    }
#pragma unroll
    for (int i = 0; i < 2; i++) {
      int slot = i * 512 + tid;
      int row = slot >> 2;
      int cp = slot & 3;
      int cl = cp ^ ((row >> 1) & 3);
      const char* gp = (const char*)(Bt + (size_t)(bn + row) * K + k0 + cl * 8);
      char* lp = Bs + (i * 512 + wave * 64) * 16;
      gload_lds16(gp, lp);
    }
    asm volatile("s_waitcnt vmcnt(0)" ::: "memory");
    __syncthreads();

    short8 af[4], bfr[4];
#pragma unroll
    for (int mi = 0; mi < 4; mi++) {
      int row = wm + mi * 16 + r16;
      if constexpr (ABYTES == 4) {
        int key = row & 7;
        f32x4 lo = *(const f32x4*)(As + (row * 8 + ((2 * g) ^ key)) * 16);
        f32x4 hi = *(const f32x4*)(As + (row * 8 + ((2 * g + 1) ^ key)) * 16);
        short8 s;
#pragma unroll
        for (int qq = 0; qq < 4; qq++) {
          s[qq] = (short)f2bf(lo[qq]);
          s[qq + 4] = (short)f2bf(hi[qq]);
        }
        af[mi] = s;
      } else {
        int key = (row >> 1) & 3;
        af[mi] = *(const short8*)(As + (row * 4 + (g ^ key)) * 16);
      }
    }
#pragma unroll
    for (int ni = 0; ni < 4; ni++) {
      int row = wn + ni * 16 + r16;
      int key = (row >> 1) & 3;
      bfr[ni] = *(const short8*)(Bs + (row * 4 + (g ^ key)) * 16);
    }
#pragma unroll
    for (int mi = 0; mi < 4; mi++)
#pragma unroll
      for (int ni = 0; ni < 4; ni++)
        acc[mi][ni] = __builtin_amdgcn_mfma_f32_16x16x32_bf16(
            af[mi], bfr[ni], acc[mi][ni], 0, 0, 0);
    __syncthreads();
  }

  // C store (bf16 h)
#pragma unroll
  for (int mi = 0; mi < 4; mi++) {
#pragma unroll
    for (int j = 0; j < 4; j++) {
      int row = bm + wm + mi * 16 + g * 4 + j;
      if (row < M) {
#pragma unroll
        for (int ni = 0; ni < 4; ni++) {
          int col = bn + wn + ni * 16 + r16;
          C[(size_t)row * N + col] = f2bf(acc[mi][ni][j]);
        }
      }
    }
  }

  // ---- fused logits epilogue ----
  if constexpr (HEADS == 8) {
    const int head = (bn + wn) >> 6;  // one head per wave (C=64)
    float asr[4], adr[4];
#pragma unroll
    for (int ni = 0; ni < 4; ni++) {
      asr[ni] = as_vec[head * 64 + ni * 16 + r16];
      adr[ni] = ad_vec[head * 64 + ni * 16 + r16];
    }
#pragma unroll
    for (int mi = 0; mi < 4; mi++) {
#pragma unroll
      for (int j = 0; j < 4; j++) {
        float ps = 0.f, pd = 0.f;
#pragma unroll
        for (int ni = 0; ni < 4; ni++) {
          ps += acc[mi][ni][j] * asr[ni];
          pd += acc[mi][ni][j] * adr[ni];
        }
#pragma unroll
        for (int off = 1; off < 16; off <<= 1) {
          ps += __shfl_xor(ps, off);
          pd += __shfl_xor(pd, off);
        }
        if (r16 == 0) {
          int row = bm + wm + mi * 16 + g * 4 + j;
          if (row < M) {
            al_s[row * 8 + head] = ps;
            al_d[row * 8 + head] = pd;
          }
        }
      }
    }
  } else {
    // HEADS==1, C=256: cross-wave reduce via LDS (reuse As as scratch)
    float* sred = (float*)As;          // [8][64]
    float* dred = sred + 512;          // [8][64]
    float asr[4], adr[4];
#pragma unroll
    for (int ni = 0; ni < 4; ni++) {
      asr[ni] = as_vec[wn + ni * 16 + r16];
      adr[ni] = ad_vec[wn + ni * 16 + r16];
    }
    __syncthreads();
#pragma unroll
    for (int mi = 0; mi < 4; mi++) {
#pragma unroll
      for (int j = 0; j < 4; j++) {
        float ps = 0.f, pd = 0.f;
#pragma unroll
        for (int ni = 0; ni < 4; ni++) {
          ps += acc[mi][ni][j] * asr[ni];
          pd += acc[mi][ni][j] * adr[ni];
        }
#pragma unroll
        for (int off = 1; off < 16; off <<= 1) {
          ps += __shfl_xor(ps, off);
          pd += __shfl_xor(pd, off);
        }
        if (r16 == 0) {
          int rloc = mi * 16 + g * 4 + j;  // 0..63 within wave
          sred[wave * 64 + rloc] = ps;
          dred[wave * 64 + rloc] = pd;
        }
      }
    }
    __syncthreads();
    if (tid < 128) {
      int base = (tid >= 64) ? 4 : 0;
      int rl = tid & 63;
      float s = sred[(base + 0) * 64 + rl] + sred[(base + 1) * 64 + rl] +
                sred[(base + 2) * 64 + rl] + sred[(base + 3) * 64 + rl];
      float d = dred[(base + 0) * 64 + rl] + dred[(base + 1) * 64 + rl] +
                dred[(base + 2) * 64 + rl] + dred[(base + 3) * 64 + rl];
      int row = bm + tid;
      if (row < M) {
        al_s[row] = s;
        al_d[row] = d;
      }
    }
  }
}

// ---------------- segment softmax + aggregation (single pass, no max) ------
__global__ void agg1(const int* __restrict__ rp, const int* __restrict__ csr,
                     const ushort* __restrict__ h1, const float* __restrict__ al_s,
                     const float* __restrict__ al_d, const float* __restrict__ b1,
                     ushort* __restrict__ h2in, int n) {
  int node = blockIdx.x * 4 + (threadIdx.x >> 6);
  if (node >= n) return;
  int lane = threadIdx.x & 63;
  int head = lane >> 3, c0 = lane * 8;
  float ad = al_d[node * 8 + head];
  int beg = rp[node], end = rp[node + 1];
  float sum = 0.f;
  float acc[8] = {};
  int j = beg;
  for (; j + 4 <= end; j += 4) {
    int s0 = csr[j], s1 = csr[j + 1], s2 = csr[j + 2], s3 = csr[j + 3];
    float e0 = al_s[s0 * 8 + head] + ad;
    float e1 = al_s[s1 * 8 + head] + ad;
    float e2 = al_s[s2 * 8 + head] + ad;
    float e3 = al_s[s3 * 8 + head] + ad;
    short8 v0 = *(const short8*)&h1[(size_t)s0 * 512 + c0];
    short8 v1 = *(const short8*)&h1[(size_t)s1 * 512 + c0];
    short8 v2 = *(const short8*)&h1[(size_t)s2 * 512 + c0];
    short8 v3 = *(const short8*)&h1[(size_t)s3 * 512 + c0];
    e0 = e0 > 0.f ? e0 : LEAKY * e0;
    e1 = e1 > 0.f ? e1 : LEAKY * e1;
    e2 = e2 > 0.f ? e2 : LEAKY * e2;
    e3 = e3 > 0.f ? e3 : LEAKY * e3;
    float p0 = __expf(e0), p1 = __expf(e1), p2 = __expf(e2), p3 = __expf(e3);
    sum += (p0 + p1) + (p2 + p3);
#pragma unroll
    for (int qq = 0; qq < 8; qq++)
      acc[qq] += p0 * bf2f((ushort)v0[qq]) + p1 * bf2f((ushort)v1[qq]) +
                 p2 * bf2f((ushort)v2[qq]) + p3 * bf2f((ushort)v3[qq]);
  }
  for (; j < end; j++) {
    int s = csr[j];
    float e = al_s[s * 8 + head] + ad;
    e = e > 0.f ? e : LEAKY * e;
    float p = __expf(e);
    sum += p;
    short8 hv = *(const short8*)&h1[(size_t)s * 512 + c0];
#pragma unroll
    for (int qq = 0; qq < 8; qq++) acc[qq] += p * bf2f((ushort)hv[qq]);
  }
  float inv = 1.0f / sum;
  short8 o;
#pragma unroll
  for (int qq = 0; qq < 8; qq++) {
    float rr = acc[qq] * inv + b1[c0 + qq];
    rr = rr > 0.f ? rr : (__expf(rr) - 1.0f);  // ELU alpha=1
    o[qq] = (short)f2bf(rr);
  }
  *(short8*)&h2in[(size_t)node * 512 + c0] = o;
}

__global__ void agg2(const int* __restrict__ rp, const int* __restrict__ csr,
                     const ushort* __restrict__ h2, const float* __restrict__ al_s,
                     const float* __restrict__ al_d, const float* __restrict__ b2,
                     float* __restrict__ out, int n) {
  int node = blockIdx.x * 4 + (threadIdx.x >> 6);
  if (node >= n) return;
  int lane = threadIdx.x & 63;
  int c0 = lane * 4;
  float ad = al_d[node];
  int beg = rp[node], end = rp[node + 1];
  float sum = 0.f;
  float a0 = 0.f, a1 = 0.f, a2 = 0.f, a3 = 0.f;
  int j = beg;
  for (; j + 4 <= end; j += 4) {
    int s0 = csr[j], s1 = csr[j + 1], s2 = csr[j + 2], s3 = csr[j + 3];
    float e0 = al_s[s0] + ad;
    float e1 = al_s[s1] + ad;
    float e2 = al_s[s2] + ad;
    float e3 = al_s[s3] + ad;
    short4v v0 = *(const short4v*)&h2[(size_t)s0 * 256 + c0];
    short4v v1 = *(const short4v*)&h2[(size_t)s1 * 256 + c0];
    short4v v2 = *(const short4v*)&h2[(size_t)s2 * 256 + c0];
    short4v v3 = *(const short4v*)&h2[(size_t)s3 * 256 + c0];
    e0 = e0 > 0.f ? e0 : LEAKY * e0;
    e1 = e1 > 0.f ? e1 : LEAKY * e1;
    e2 = e2 > 0.f ? e2 : LEAKY * e2;
    e3 = e3 > 0.f ? e3 : LEAKY * e3;
    float p0 = __expf(e0), p1 = __expf(e1), p2 = __expf(e2), p3 = __expf(e3);
    sum += (p0 + p1) + (p2 + p3);
    a0 += p0 * bf2f((ushort)v0[0]) + p1 * bf2f((ushort)v1[0]) +
          p2 * bf2f((ushort)v2[0]) + p3 * bf2f((ushort)v3[0]);
    a1 += p0 * bf2f((ushort)v0[1]) + p1 * bf2f((ushort)v1[1]) +
          p2 * bf2f((ushort)v2[1]) + p3 * bf2f((ushort)v3[1]);
    a2 += p0 * bf2f((ushort)v0[2]) + p1 * bf2f((ushort)v1[2]) +
          p2 * bf2f((ushort)v2[2]) + p3 * bf2f((ushort)v3[2]);
    a3 += p0 * bf2f((ushort)v0[3]) + p1 * bf2f((ushort)v1[3]) +
          p2 * bf2f((ushort)v2[3]) + p3 * bf2f((ushort)v3[3]);
  }
  for (; j < end; j++) {
    int s = csr[j];
    float e = al_s[s] + ad;
    e = e > 0.f ? e : LEAKY * e;
    float p = __expf(e);
    sum += p;
    short4v hv = *(const short4v*)&h2[(size_t)s * 256 + c0];
    a0 += p * bf2f((ushort)hv[0]);
    a1 += p * bf2f((ushort)hv[1]);
    a2 += p * bf2f((ushort)hv[2]);
    a3 += p * bf2f((ushort)hv[3]);
  }
  float inv = 1.0f / sum;
  f32x4 o;
  o[0] = a0 * inv + b2[c0 + 0];
  o[1] = a1 * inv + b2[c0 + 1];
  o[2] = a2 * inv + b2[c0 + 2];
  o[3] = a3 * inv + b2[c0 + 3];
  *(f32x4*)&out[(size_t)node * 256 + c0] = o;
}

// ---------------------------------------------------------------------------
extern "C" void kernel_launch(void* const* d_in, const int* in_sizes, int n_in,
                              void* d_out, int out_size, void* d_ws, size_t ws_size,
                              hipStream_t stream) {
  const float* x = (const float*)d_in[0];
  const int* ei = (const int*)d_in[1];
  const float* W1 = (const float*)d_in[2];
  const float* a1s = (const float*)d_in[3];
  const float* a1d = (const float*)d_in[4];
  const float* b1 = (const float*)d_in[5];
  const float* W2 = (const float*)d_in[6];
  const float* a2s = (const float*)d_in[7];
  const float* a2d = (const float*)d_in[8];
  const float* b2 = (const float*)d_in[9];
  float* out = (float*)d_out;

  const int n = in_sizes[0] / 1024;  // 30000
  const int E = in_sizes[1] / 2;     // 480000
  const int K1 = 1024, C1 = 512, C2 = 256;

  char* ws = (char*)d_ws;
  ushort* h1 = (ushort*)(ws + 0);            // [n,512] bf16
  ushort* h2in = (ushort*)(ws + 31000000);   // [n,512] bf16 (elu out)
  ushort* h2 = (ushort*)(ws + 62000000);     // [n,256] bf16
  float* al_s = (float*)(ws + 78000000);     // [n,8]
  float* al_d = (float*)(ws + 79000000);     // [n,8]
  float* al2s = (float*)(ws + 80000000);     // [n]
  float* al2d = (float*)(ws + 80200000);     // [n]
  ushort* W1t = (ushort*)(ws + 80400000);    // [512,1024] bf16
  ushort* W2t = (ushort*)(ws + 81600000);    // [256,512] bf16
  int* cnt = (int*)(ws + 82000000);          // [n]
  int* rp = (int*)(ws + 82200000);           // [n+1]
  int* fill = (int*)(ws + 82400000);         // [n]
  int* csr = (int*)(ws + 82600000);          // [E+n]

  const int* esrc = ei;
  const int* edst = ei + E;
  const int ET = E + n;

  convw_all<<<(C1 * K1 + C2 * C1 + 255) / 256, 256, 0, stream>>>(
      W1, W1t, W2, W2t, cnt, fill, n);
  hist<<<(ET + 255) / 256, 256, 0, stream>>>(edst, E, n, cnt);
  scan_fast<<<1, 1024, 0, stream>>>(cnt, rp, n);
  scatter<<<(ET + 255) / 256, 256, 0, stream>>>(esrc, edst, E, n, rp, fill, csr);

  const int gx1 = ((n + 127) / 128) * (C1 / 256);
  gemm_fl<4, 8><<<gx1, 512, 0, stream>>>(x, W1t, h1, al_s, al_d, a1s, a1d, n, K1, C1);
  agg1<<<(n + 3) / 4, 256, 0, stream>>>(rp, csr, h1, al_s, al_d, b1, h2in, n);

  const int gx2 = ((n + 127) / 128) * (C2 / 256);
  gemm_fl<2, 1><<<gx2, 512, 0, stream>>>(h2in, W2t, h2, al2s, al2d, a2s, a2d, n, C1, C2);
  agg2<<<(n + 3) / 4, 256, 0, stream>>>(rp, csr, h2, al2s, al2d, b2, out, n);
}

// Round 12
// 269.147 us; speedup vs baseline: 1.1015x; 1.0069x over previous
//
#include <hip/hip_runtime.h>
#include <hip/hip_bf16.h>

typedef unsigned int uint;
typedef unsigned short ushort;
typedef __attribute__((ext_vector_type(8))) short short8;
typedef __attribute__((ext_vector_type(4))) short short4v;
typedef __attribute__((ext_vector_type(4))) float f32x4;

#define LEAKY 0.2f

__device__ __forceinline__ ushort f2bf(float f) {
  __hip_bfloat16 h = __float2bfloat16(f);
  return __builtin_bit_cast(ushort, h);
}
__device__ __forceinline__ float bf2f(ushort u) {
  uint v = ((uint)u) << 16;
  return __builtin_bit_cast(float, v);
}
__device__ __forceinline__ void gload_lds16(const void* g, void* l) {
  __builtin_amdgcn_global_load_lds(
      (const __attribute__((address_space(1))) void*)g,
      (__attribute__((address_space(3))) void*)l, 16, 0, 0);
}

// ---- both W transposes + bf16 convert + cnt/fill zeroing, one launch ------
__global__ void convw_all(const float* __restrict__ W1, ushort* __restrict__ W1t,
                          const float* __restrict__ W2, ushort* __restrict__ W2t,
                          int* __restrict__ cnt, int* __restrict__ fill, int n) {
  int idx = blockIdx.x * 256 + threadIdx.x;
  if (idx < n) { cnt[idx] = 0; fill[idx] = 0; }
  const int n1 = 512 * 1024;
  if (idx < n1) {
    int nrow = idx >> 10, k = idx & 1023;
    W1t[idx] = f2bf(W1[(size_t)k * 512 + nrow]);
  } else {
    idx -= n1;
    if (idx < 256 * 512) {
      int nrow = idx >> 9, k = idx & 511;
      W2t[idx] = f2bf(W2[(size_t)k * 256 + nrow]);
    }
  }
}

// ---------------- CSR build ------------------------------------------------
__global__ void hist(const int* __restrict__ dst, int E, int n, int* cnt) {
  int e = blockIdx.x * 256 + threadIdx.x;
  if (e >= E + n) return;
  int d = (e < E) ? dst[e] : (e - E);
  atomicAdd(&cnt[d], 1);
}

// single-block scan, shfl-based (few barriers). n <= 32768.
__global__ __launch_bounds__(1024) void scan_fast(const int* __restrict__ cnt,
                                                  int* __restrict__ rp, int n) {
  __shared__ int wsum[16];
  __shared__ int woff[16];
  const int t = threadIdx.x;
  const int per = (n + 1023) / 1024;
  const int base = t * per;
  int local[32];
  int s = 0;
#pragma unroll
  for (int i = 0; i < 32; i++) {
    if (i >= per) break;
    int idx = base + i;
    int v = (idx < n) ? cnt[idx] : 0;
    local[i] = s;
    s += v;
  }
  const int lane = t & 63, wave = t >> 6;
  int incl = s;
#pragma unroll
  for (int off = 1; off < 64; off <<= 1) {
    int v = __shfl_up(incl, off);
    if (lane >= off) incl += v;
  }
  if (lane == 63) wsum[wave] = incl;
  __syncthreads();
  if (wave == 0 && lane < 16) {
    int v = wsum[lane];
    int wi = v;
#pragma unroll
    for (int off = 1; off < 16; off <<= 1) {
      int u = __shfl_up(wi, off);
      if (lane >= off) wi += u;
    }
    woff[lane] = wi - v;  // exclusive
  }
  __syncthreads();
  const int gexcl = woff[wave] + (incl - s);
#pragma unroll
  for (int i = 0; i < 32; i++) {
    if (i >= per) break;
    int idx = base + i;
    if (idx < n) rp[idx] = gexcl + local[i];
  }
  if (t == 1023) rp[n] = woff[15] + incl;
}

__global__ void scatter(const int* __restrict__ src, const int* __restrict__ dst,
                        int E, int n, const int* __restrict__ rp,
                        int* fill, int* __restrict__ csr) {
  int e = blockIdx.x * 256 + threadIdx.x;
  if (e >= E + n) return;
  int s, d;
  if (e < E) { s = src[e]; d = dst[e]; } else { s = d = e - E; }
  int pos = rp[d] + atomicAdd(&fill[d], 1);
  csr[pos] = s;
}

// ------- R3-proven wide GEMM + fused logit epilogue + XCD swizzle ----------
// C[M,N]=A[M,K]*Bt[N,K]^T, h stored bf16. 512 thr, 8 waves (2Mx4N),
// BM=128 BN=256 BK=32, single-buffer LDS, stage->vmcnt(0)->barrier loop.
// This round's single variable: bijective XCD-chunked blockIdx swizzle
// (m204) so A-sharing neighbor blocks land on one XCD's L2 -> staging loads
// L2-hit -> shorter vmcnt(0) drains (R4 showed FETCH 122->65MB; confound
// removed here).
template <int ABYTES, int HEADS>
__global__ __launch_bounds__(512) void gemm_fl(
    const void* __restrict__ Av, const ushort* __restrict__ Bt,
    ushort* __restrict__ C, float* __restrict__ al_s, float* __restrict__ al_d,
    const float* __restrict__ as_vec, const float* __restrict__ ad_vec,
    int M, int K, int N) {
  constexpr int BM = 128, BN = 256, BK = 32;
  constexpr int SPRA = (BK * ABYTES) / 16;
  constexpr int A_ITER = (BM * SPRA) / 512;
  __shared__ __align__(16) char As[BM * BK * ABYTES];  // 16KB / 8KB
  __shared__ __align__(16) char Bs[BN * BK * 2];       // 16KB
  const int tid = threadIdx.x;
  const int wave = tid >> 6, lane = tid & 63;
  const int g = lane >> 4, r16 = lane & 15;

  // bijective XCD-chunked swizzle (m204): works for any nwg
  const int nwg = (int)gridDim.x;
  const int q = nwg >> 3, r = nwg & 7;
  const int xcd = (int)blockIdx.x & 7, pos = (int)blockIdx.x >> 3;
  const int wgid = (xcd < r ? xcd * (q + 1) : r * (q + 1) + (xcd - r) * q) + pos;

  const int nby = N / BN;
  const int bx = wgid / nby;
  const int by = wgid - bx * nby;
  const int bm = bx * BM, bn = by * BN;
  const int wm = (wave >> 2) * 64, wn = (wave & 3) * 64;

  f32x4 acc[4][4] = {};
  const char* A = (const char*)Av;

  for (int k0 = 0; k0 < K; k0 += BK) {
#pragma unroll
    for (int i = 0; i < A_ITER; i++) {
      int slot = i * 512 + tid;
      int row = slot / SPRA;
      int cp = slot - row * SPRA;
      int key = (ABYTES == 4) ? (row & 7) : ((row >> 1) & 3);
      int cl = cp ^ key;
      int arow = bm + row;
      arow = arow < M ? arow : M - 1;
      const char* gp = A + ((size_t)arow * K + k0) * ABYTES + cl * 16;
      char* lp = As + (i * 512 + wave * 64) * 16;
      gload_lds16(gp, lp);
    }
#pragma unroll
    for (int i = 0; i < 2; i++) {
      int slot = i * 512 + tid;
      int row = slot >> 2;
      int cp = slot & 3;
      int cl = cp ^ ((row >> 1) & 3);
      const char* gp = (const char*)(Bt + (size_t)(bn + row) * K + k0 + cl * 8);
      char* lp = Bs + (i * 512 + wave * 64) * 16;
      gload_lds16(gp, lp);
    }
    asm volatile("s_waitcnt vmcnt(0)" ::: "memory");
    __syncthreads();

    short8 af[4], bfr[4];
#pragma unroll
    for (int mi = 0; mi < 4; mi++) {
      int row = wm + mi * 16 + r16;
      if constexpr (ABYTES == 4) {
        int key = row & 7;
        f32x4 lo = *(const f32x4*)(As + (row * 8 + ((2 * g) ^ key)) * 16);
        f32x4 hi = *(const f32x4*)(As + (row * 8 + ((2 * g + 1) ^ key)) * 16);
        short8 s;
#pragma unroll
        for (int qq = 0; qq < 4; qq++) {
          s[qq] = (short)f2bf(lo[qq]);
          s[qq + 4] = (short)f2bf(hi[qq]);
        }
        af[mi] = s;
      } else {
        int key = (row >> 1) & 3;
        af[mi] = *(const short8*)(As + (row * 4 + (g ^ key)) * 16);
      }
    }
#pragma unroll
    for (int ni = 0; ni < 4; ni++) {
      int row = wn + ni * 16 + r16;
      int key = (row >> 1) & 3;
      bfr[ni] = *(const short8*)(Bs + (row * 4 + (g ^ key)) * 16);
    }
#pragma unroll
    for (int mi = 0; mi < 4; mi++)
#pragma unroll
      for (int ni = 0; ni < 4; ni++)
        acc[mi][ni] = __builtin_amdgcn_mfma_f32_16x16x32_bf16(
            af[mi], bfr[ni], acc[mi][ni], 0, 0, 0);
    __syncthreads();
  }

  // C store (bf16 h)
#pragma unroll
  for (int mi = 0; mi < 4; mi++) {
#pragma unroll
    for (int j = 0; j < 4; j++) {
      int row = bm + wm + mi * 16 + g * 4 + j;
      if (row < M) {
#pragma unroll
        for (int ni = 0; ni < 4; ni++) {
          int col = bn + wn + ni * 16 + r16;
          C[(size_t)row * N + col] = f2bf(acc[mi][ni][j]);
        }
      }
    }
  }

  // ---- fused logits epilogue ----
  if constexpr (HEADS == 8) {
    const int head = (bn + wn) >> 6;  // one head per wave (C=64)
    float asr[4], adr[4];
#pragma unroll
    for (int ni = 0; ni < 4; ni++) {
      asr[ni] = as_vec[head * 64 + ni * 16 + r16];
      adr[ni] = ad_vec[head * 64 + ni * 16 + r16];
    }
#pragma unroll
    for (int mi = 0; mi < 4; mi++) {
#pragma unroll
      for (int j = 0; j < 4; j++) {
        float ps = 0.f, pd = 0.f;
#pragma unroll
        for (int ni = 0; ni < 4; ni++) {
          ps += acc[mi][ni][j] * asr[ni];
          pd += acc[mi][ni][j] * adr[ni];
        }
#pragma unroll
        for (int off = 1; off < 16; off <<= 1) {
          ps += __shfl_xor(ps, off);
          pd += __shfl_xor(pd, off);
        }
        if (r16 == 0) {
          int row = bm + wm + mi * 16 + g * 4 + j;
          if (row < M) {
            al_s[row * 8 + head] = ps;
            al_d[row * 8 + head] = pd;
          }
        }
      }
    }
  } else {
    // HEADS==1, C=256: cross-wave reduce via LDS (reuse As as scratch)
    float* sred = (float*)As;          // [8][64]
    float* dred = sred + 512;          // [8][64]
    float asr[4], adr[4];
#pragma unroll
    for (int ni = 0; ni < 4; ni++) {
      asr[ni] = as_vec[wn + ni * 16 + r16];
      adr[ni] = ad_vec[wn + ni * 16 + r16];
    }
    __syncthreads();
#pragma unroll
    for (int mi = 0; mi < 4; mi++) {
#pragma unroll
      for (int j = 0; j < 4; j++) {
        float ps = 0.f, pd = 0.f;
#pragma unroll
        for (int ni = 0; ni < 4; ni++) {
          ps += acc[mi][ni][j] * asr[ni];
          pd += acc[mi][ni][j] * adr[ni];
        }
#pragma unroll
        for (int off = 1; off < 16; off <<= 1) {
          ps += __shfl_xor(ps, off);
          pd += __shfl_xor(pd, off);
        }
        if (r16 == 0) {
          int rloc = mi * 16 + g * 4 + j;  // 0..63 within wave
          sred[wave * 64 + rloc] = ps;
          dred[wave * 64 + rloc] = pd;
        }
      }
    }
    __syncthreads();
    if (tid < 128) {
      int base = (tid >= 64) ? 4 : 0;
      int rl = tid & 63;
      float s = sred[(base + 0) * 64 + rl] + sred[(base + 1) * 64 + rl] +
                sred[(base + 2) * 64 + rl] + sred[(base + 3) * 64 + rl];
      float d = dred[(base + 0) * 64 + rl] + dred[(base + 1) * 64 + rl] +
                dred[(base + 2) * 64 + rl] + dred[(base + 3) * 64 + rl];
      int row = bm + tid;
      if (row < M) {
        al_s[row] = s;
        al_d[row] = d;
      }
    }
  }
}

// ---------------- segment softmax + aggregation (single pass, no max) ------
__global__ void agg1(const int* __restrict__ rp, const int* __restrict__ csr,
                     const ushort* __restrict__ h1, const float* __restrict__ al_s,
                     const float* __restrict__ al_d, const float* __restrict__ b1,
                     ushort* __restrict__ h2in, int n) {
  int node = blockIdx.x * 4 + (threadIdx.x >> 6);
  if (node >= n) return;
  int lane = threadIdx.x & 63;
  int head = lane >> 3, c0 = lane * 8;
  float ad = al_d[node * 8 + head];
  int beg = rp[node], end = rp[node + 1];
  float sum = 0.f;
  float acc[8] = {};
  int j = beg;
  for (; j + 4 <= end; j += 4) {
    int s0 = csr[j], s1 = csr[j + 1], s2 = csr[j + 2], s3 = csr[j + 3];
    float e0 = al_s[s0 * 8 + head] + ad;
    float e1 = al_s[s1 * 8 + head] + ad;
    float e2 = al_s[s2 * 8 + head] + ad;
    float e3 = al_s[s3 * 8 + head] + ad;
    short8 v0 = *(const short8*)&h1[(size_t)s0 * 512 + c0];
    short8 v1 = *(const short8*)&h1[(size_t)s1 * 512 + c0];
    short8 v2 = *(const short8*)&h1[(size_t)s2 * 512 + c0];
    short8 v3 = *(const short8*)&h1[(size_t)s3 * 512 + c0];
    e0 = e0 > 0.f ? e0 : LEAKY * e0;
    e1 = e1 > 0.f ? e1 : LEAKY * e1;
    e2 = e2 > 0.f ? e2 : LEAKY * e2;
    e3 = e3 > 0.f ? e3 : LEAKY * e3;
    float p0 = __expf(e0), p1 = __expf(e1), p2 = __expf(e2), p3 = __expf(e3);
    sum += (p0 + p1) + (p2 + p3);
#pragma unroll
    for (int qq = 0; qq < 8; qq++)
      acc[qq] += p0 * bf2f((ushort)v0[qq]) + p1 * bf2f((ushort)v1[qq]) +
                 p2 * bf2f((ushort)v2[qq]) + p3 * bf2f((ushort)v3[qq]);
  }
  for (; j < end; j++) {
    int s = csr[j];
    float e = al_s[s * 8 + head] + ad;
    e = e > 0.f ? e : LEAKY * e;
    float p = __expf(e);
    sum += p;
    short8 hv = *(const short8*)&h1[(size_t)s * 512 + c0];
#pragma unroll
    for (int qq = 0; qq < 8; qq++) acc[qq] += p * bf2f((ushort)hv[qq]);
  }
  float inv = 1.0f / sum;
  short8 o;
#pragma unroll
  for (int qq = 0; qq < 8; qq++) {
    float rr = acc[qq] * inv + b1[c0 + qq];
    rr = rr > 0.f ? rr : (__expf(rr) - 1.0f);  // ELU alpha=1
    o[qq] = (short)f2bf(rr);
  }
  *(short8*)&h2in[(size_t)node * 512 + c0] = o;
}

__global__ void agg2(const int* __restrict__ rp, const int* __restrict__ csr,
                     const ushort* __restrict__ h2, const float* __restrict__ al_s,
                     const float* __restrict__ al_d, const float* __restrict__ b2,
                     float* __restrict__ out, int n) {
  int node = blockIdx.x * 4 + (threadIdx.x >> 6);
  if (node >= n) return;
  int lane = threadIdx.x & 63;
  int c0 = lane * 4;
  float ad = al_d[node];
  int beg = rp[node], end = rp[node + 1];
  float sum = 0.f;
  float a0 = 0.f, a1 = 0.f, a2 = 0.f, a3 = 0.f;
  int j = beg;
  for (; j + 4 <= end; j += 4) {
    int s0 = csr[j], s1 = csr[j + 1], s2 = csr[j + 2], s3 = csr[j + 3];
    float e0 = al_s[s0] + ad;
    float e1 = al_s[s1] + ad;
    float e2 = al_s[s2] + ad;
    float e3 = al_s[s3] + ad;
    short4v v0 = *(const short4v*)&h2[(size_t)s0 * 256 + c0];
    short4v v1 = *(const short4v*)&h2[(size_t)s1 * 256 + c0];
    short4v v2 = *(const short4v*)&h2[(size_t)s2 * 256 + c0];
    short4v v3 = *(const short4v*)&h2[(size_t)s3 * 256 + c0];
    e0 = e0 > 0.f ? e0 : LEAKY * e0;
    e1 = e1 > 0.f ? e1 : LEAKY * e1;
    e2 = e2 > 0.f ? e2 : LEAKY * e2;
    e3 = e3 > 0.f ? e3 : LEAKY * e3;
    float p0 = __expf(e0), p1 = __expf(e1), p2 = __expf(e2), p3 = __expf(e3);
    sum += (p0 + p1) + (p2 + p3);
    a0 += p0 * bf2f((ushort)v0[0]) + p1 * bf2f((ushort)v1[0]) +
          p2 * bf2f((ushort)v2[0]) + p3 * bf2f((ushort)v3[0]);
    a1 += p0 * bf2f((ushort)v0[1]) + p1 * bf2f((ushort)v1[1]) +
          p2 * bf2f((ushort)v2[1]) + p3 * bf2f((ushort)v3[1]);
    a2 += p0 * bf2f((ushort)v0[2]) + p1 * bf2f((ushort)v1[2]) +
          p2 * bf2f((ushort)v2[2]) + p3 * bf2f((ushort)v3[2]);
    a3 += p0 * bf2f((ushort)v0[3]) + p1 * bf2f((ushort)v1[3]) +
          p2 * bf2f((ushort)v2[3]) + p3 * bf2f((ushort)v3[3]);
  }
  for (; j < end; j++) {
    int s = csr[j];
    float e = al_s[s] + ad;
    e = e > 0.f ? e : LEAKY * e;
    float p = __expf(e);
    sum += p;
    short4v hv = *(const short4v*)&h2[(size_t)s * 256 + c0];
    a0 += p * bf2f((ushort)hv[0]);
    a1 += p * bf2f((ushort)hv[1]);
    a2 += p * bf2f((ushort)hv[2]);
    a3 += p * bf2f((ushort)hv[3]);
  }
  float inv = 1.0f / sum;
  f32x4 o;
  o[0] = a0 * inv + b2[c0 + 0];
  o[1] = a1 * inv + b2[c0 + 1];
  o[2] = a2 * inv + b2[c0 + 2];
  o[3] = a3 * inv + b2[c0 + 3];
  *(f32x4*)&out[(size_t)node * 256 + c0] = o;
}

// ---------------------------------------------------------------------------
extern "C" void kernel_launch(void* const* d_in, const int* in_sizes, int n_in,
                              void* d_out, int out_size, void* d_ws, size_t ws_size,
                              hipStream_t stream) {
  const float* x = (const float*)d_in[0];
  const int* ei = (const int*)d_in[1];
  const float* W1 = (const float*)d_in[2];
  const float* a1s = (const float*)d_in[3];
  const float* a1d = (const float*)d_in[4];
  const float* b1 = (const float*)d_in[5];
  const float* W2 = (const float*)d_in[6];
  const float* a2s = (const float*)d_in[7];
  const float* a2d = (const float*)d_in[8];
  const float* b2 = (const float*)d_in[9];
  float* out = (float*)d_out;

  const int n = in_sizes[0] / 1024;  // 30000
  const int E = in_sizes[1] / 2;     // 480000
  const int K1 = 1024, C1 = 512, C2 = 256;

  char* ws = (char*)d_ws;
  ushort* h1 = (ushort*)(ws + 0);            // [n,512] bf16
  ushort* h2in = (ushort*)(ws + 31000000);   // [n,512] bf16 (elu out)
  ushort* h2 = (ushort*)(ws + 62000000);     // [n,256] bf16
  float* al_s = (float*)(ws + 78000000);     // [n,8]
  float* al_d = (float*)(ws + 79000000);     // [n,8]
  float* al2s = (float*)(ws + 80000000);     // [n]
  float* al2d = (float*)(ws + 80200000);     // [n]
  ushort* W1t = (ushort*)(ws + 80400000);    // [512,1024] bf16
  ushort* W2t = (ushort*)(ws + 81600000);    // [256,512] bf16
  int* cnt = (int*)(ws + 82000000);          // [n]
  int* rp = (int*)(ws + 82200000);           // [n+1]
  int* fill = (int*)(ws + 82400000);         // [n]
  int* csr = (int*)(ws + 82600000);          // [E+n]

  const int* esrc = ei;
  const int* edst = ei + E;
  const int ET = E + n;

  convw_all<<<(C1 * K1 + C2 * C1 + 255) / 256, 256, 0, stream>>>(
      W1, W1t, W2, W2t, cnt, fill, n);
  hist<<<(ET + 255) / 256, 256, 0, stream>>>(edst, E, n, cnt);
  scan_fast<<<1, 1024, 0, stream>>>(cnt, rp, n);
  scatter<<<(ET + 255) / 256, 256, 0, stream>>>(esrc, edst, E, n, rp, fill, csr);

  const int gx1 = ((n + 127) / 128) * (C1 / 256);
  gemm_fl<4, 8><<<gx1, 512, 0, stream>>>(x, W1t, h1, al_s, al_d, a1s, a1d, n, K1, C1);
  agg1<<<(n + 3) / 4, 256, 0, stream>>>(rp, csr, h1, al_s, al_d, b1, h2in, n);

  const int gx2 = ((n + 127) / 128) * (C2 / 256);
  gemm_fl<2, 1><<<gx2, 512, 0, stream>>>(h2in, W2t, h2, al2s, al2d, a2s, a2d, n, C1, C2);
  agg2<<<(n + 3) / 4, 256, 0, stream>>>(rp, csr, h2, al2s, al2d, b2, out, n);
}